// Round 3
// baseline (9695.988 us; speedup 1.0000x reference)
//
#include <hip/hip_runtime.h>
#include <hip/hip_bf16.h>
#include <math.h>

#define N_NODES 100000
#define F_IN    500
#define HID     64
#define NCLS    47
#define CP2     64      // f16 row stride for propagation buffers: 128B = 2 lines, aligned
#define N_EDGE  3200000
#define K_PROP  10
#define NBUCK   1563    // ceil(N_NODES/64)

typedef _Float16 v8h  __attribute__((ext_vector_type(8)));
typedef _Float16 v4hh __attribute__((ext_vector_type(4)));
typedef float    v4f  __attribute__((ext_vector_type(4)));

// ---------------------------------------------------------------------------
// GEMM1: h[N,64] = relu(x[N,500] @ W1[500,64] + b1), f16 output for GEMM2.
// ---------------------------------------------------------------------------
__global__ __launch_bounds__(256) void gemm1_relu(
    const float* __restrict__ x, const float* __restrict__ W1,
    const float* __restrict__ b1, _Float16* __restrict__ h)
{
  __shared__ _Float16 xa[128][40];   // stride 40 f16 = 80B: 8B-aligned frags, 2-way banks
  __shared__ _Float16 wb[64][40];    // W1 tile transposed: wb[col][k]
  const int tid  = threadIdx.x;
  const int lane = tid & 63;
  const int wv   = tid >> 6;
  const int l15  = lane & 15;
  const int quad = lane >> 4;
  const int row0 = blockIdx.x * 128;

  v4f acc[2][4] = {};

  for (int k0 = 0; k0 < F_IN; k0 += 32) {
    #pragma unroll
    for (int i = 0; i < 4; ++i) {
      int f = tid + i * 256;
      int r = f >> 3, q = f & 7;
      int gr = row0 + r;
      int kk = k0 + q * 4;
      float v0 = 0.f, v1 = 0.f, v2 = 0.f, v3 = 0.f;
      if (gr < N_NODES) {
        if (kk + 3 < F_IN) {
          const float4 v = *(const float4*)(x + (size_t)gr * F_IN + kk);
          v0 = v.x; v1 = v.y; v2 = v.z; v3 = v.w;
        } else {
          const float* xp = x + (size_t)gr * F_IN;
          if (kk + 0 < F_IN) v0 = xp[kk + 0];
          if (kk + 1 < F_IN) v1 = xp[kk + 1];
          if (kk + 2 < F_IN) v2 = xp[kk + 2];
          if (kk + 3 < F_IN) v3 = xp[kk + 3];
        }
      }
      v4hh pk = {(_Float16)v0, (_Float16)v1, (_Float16)v2, (_Float16)v3};
      *(v4hh*)&xa[r][q * 4] = pk;            // one 8B LDS store
    }
    #pragma unroll
    for (int i = 0; i < 2; ++i) {
      int f = tid + i * 256;
      int k = f >> 4, c4 = (f & 15) * 4;
      int gk = k0 + k;
      float4 v = make_float4(0.f, 0.f, 0.f, 0.f);
      if (gk < F_IN) v = *(const float4*)(W1 + (size_t)gk * HID + c4);
      wb[c4 + 0][k] = (_Float16)v.x; wb[c4 + 1][k] = (_Float16)v.y;
      wb[c4 + 2][k] = (_Float16)v.z; wb[c4 + 3][k] = (_Float16)v.w;
    }
    __syncthreads();
    const int m0 = wv * 32;
    v8h a0 = *(const v8h*)&xa[m0 + l15][quad * 8];
    v8h a1 = *(const v8h*)&xa[m0 + 16 + l15][quad * 8];
    #pragma unroll
    for (int nt = 0; nt < 4; ++nt) {
      v8h b = *(const v8h*)&wb[nt * 16 + l15][quad * 8];
      acc[0][nt] = __builtin_amdgcn_mfma_f32_16x16x32_f16(a0, b, acc[0][nt], 0, 0, 0);
      acc[1][nt] = __builtin_amdgcn_mfma_f32_16x16x32_f16(a1, b, acc[1][nt], 0, 0, 0);
    }
    __syncthreads();
  }
  const int m0 = wv * 32;
  float b1v[4];
  #pragma unroll
  for (int nt = 0; nt < 4; ++nt) b1v[nt] = b1[nt * 16 + l15];
  #pragma unroll
  for (int mi = 0; mi < 2; ++mi)
    #pragma unroll
    for (int r = 0; r < 4; ++r) {
      int grow = row0 + m0 + mi * 16 + quad * 4 + r;
      if (grow < N_NODES) {
        #pragma unroll
        for (int nt = 0; nt < 4; ++nt) {
          float v = fmaxf(acc[mi][nt][r] + b1v[nt], 0.f);
          h[(size_t)grow * HID + nt * 16 + l15] = (_Float16)v;
        }
      }
    }
}

// ---------------------------------------------------------------------------
// GEMM2 fused: z = h @ W2 + b2 ; out_ls = log_softmax(z) ; out_hid = temp0*z ;
// cur = z (f16, stride CP2).
// ---------------------------------------------------------------------------
__global__ __launch_bounds__(256) void gemm2_fused(
    const _Float16* __restrict__ h, const float* __restrict__ W2,
    const float* __restrict__ b2, const float* __restrict__ temp,
    float* __restrict__ out_ls, float* __restrict__ out_hid,
    _Float16* __restrict__ cur)
{
  __shared__ _Float16 ha[128][72];
  __shared__ _Float16 wb[64][72];
  __shared__ float b2s[64];
  const int tid  = threadIdx.x;
  const int lane = tid & 63;
  const int wv   = tid >> 6;
  const int l15  = lane & 15;
  const int quad = lane >> 4;
  const int row0 = blockIdx.x * 128;

  for (int i = tid; i < 64 * 72; i += 256) ((_Float16*)wb)[i] = (_Float16)0.f;
  if (tid < 64) b2s[tid] = (tid < NCLS) ? b2[tid] : 0.f;
  __syncthreads();
  for (int i = tid; i < HID * NCLS; i += 256) {
    int k = i / NCLS, n = i % NCLS;
    wb[n][k] = (_Float16)W2[i];
  }
  const unsigned short* hu = (const unsigned short*)h;
  #pragma unroll
  for (int i = 0; i < 8; ++i) {
    int f = tid + i * 256;
    int r = f >> 4, q = (f & 15) * 4;
    int gr = row0 + r;
    ushort4 v = make_ushort4(0, 0, 0, 0);
    if (gr < N_NODES) v = *(const ushort4*)(hu + (size_t)gr * HID + q);
    *(ushort4*)((unsigned short*)&ha[r][0] + q) = v;
  }
  __syncthreads();

  const int m0 = wv * 32;
  v4f acc[2][4] = {};
  #pragma unroll
  for (int ks = 0; ks < 2; ++ks) {
    v8h a0 = *(const v8h*)&ha[m0 + l15][ks * 32 + quad * 8];
    v8h a1 = *(const v8h*)&ha[m0 + 16 + l15][ks * 32 + quad * 8];
    #pragma unroll
    for (int nt = 0; nt < 4; ++nt) {
      v8h b = *(const v8h*)&wb[nt * 16 + l15][ks * 32 + quad * 8];
      acc[0][nt] = __builtin_amdgcn_mfma_f32_16x16x32_f16(a0, b, acc[0][nt], 0, 0, 0);
      acc[1][nt] = __builtin_amdgcn_mfma_f32_16x16x32_f16(a1, b, acc[1][nt], 0, 0, 0);
    }
  }

  const float t0 = temp[0];
  float b2v[4];
  #pragma unroll
  for (int nt = 0; nt < 4; ++nt) b2v[nt] = b2s[nt * 16 + l15];

  #pragma unroll
  for (int mi = 0; mi < 2; ++mi)
    #pragma unroll
    for (int r = 0; r < 4; ++r) {
      int grow = row0 + m0 + mi * 16 + quad * 4 + r;
      float v[4]; float mx = -1e30f;
      #pragma unroll
      for (int nt = 0; nt < 4; ++nt) {
        v[nt] = acc[mi][nt][r] + b2v[nt];
        if (nt * 16 + l15 < NCLS) mx = fmaxf(mx, v[nt]);
      }
      #pragma unroll
      for (int off = 1; off < 16; off <<= 1) mx = fmaxf(mx, __shfl_xor(mx, off));
      float s = 0.f;
      #pragma unroll
      for (int nt = 0; nt < 4; ++nt)
        if (nt * 16 + l15 < NCLS) s += __expf(v[nt] - mx);
      #pragma unroll
      for (int off = 1; off < 16; off <<= 1) s += __shfl_xor(s, off);
      float den = mx + __logf(s);
      if (grow < N_NODES) {
        #pragma unroll
        for (int nt = 0; nt < 4; ++nt) {
          int c = nt * 16 + l15;
          if (c < NCLS) {
            float z = v[nt];
            out_ls [(size_t)grow * NCLS + c] = z - den;
            out_hid[(size_t)grow * NCLS + c] = t0 * z;
            cur    [(size_t)grow * CP2  + c] = (_Float16)z;
          }
        }
      }
    }
}

// ---------------------------------------------------------------------------
// Graph prep: per-node in-degree counts -> dis + per-bucket segments -> fill
// ---------------------------------------------------------------------------
__global__ void init_counts(int* counts, int* cursor)
{
  int i = blockIdx.x * 256 + threadIdx.x;
  if (i < N_NODES) counts[i] = 0;
  if (i == 0) *cursor = 0;
}

__global__ void count_edges(const int* __restrict__ col, int* __restrict__ counts)
{
  int e = blockIdx.x * 256 + threadIdx.x;
  if (e < N_EDGE) atomicAdd(&counts[col[e]], 1);
}

// per bucket (64 dst nodes): segment base via wave-scan + one cursor atomic.
// Segment sizes rounded up to even so every bucket start is 16B-aligned.
__global__ void bucket_scan(const int* __restrict__ counts, float* __restrict__ dis,
                            int* __restrict__ bstart, int* __restrict__ bcnt,
                            int* __restrict__ bcur, int* __restrict__ cursor)
{
  int b = blockIdx.x * 256 + threadIdx.x;
  int lane = threadIdx.x & 63;
  int s = 0;
  if (b < NBUCK) {
    int base = b * 64;
    int lim = (N_NODES - base < 64) ? (N_NODES - base) : 64;
    for (int j = 0; j < lim; ++j) {
      int c = counts[base + j];
      s += c;
      dis[base + j] = rsqrtf((float)(c + 1));   // deg = in-edges + self loop
    }
  }
  int sz = (s + 1) & ~1;
  int incl = sz;
  #pragma unroll
  for (int off = 1; off < 64; off <<= 1) {
    int t = __shfl_up(incl, off);
    if (lane >= off) incl += t;
  }
  int base0 = 0;
  if (lane == 63) base0 = atomicAdd(cursor, incl);
  base0 = __shfl(base0, 63);
  if (b < NBUCK) {
    int st = base0 + incl - sz;
    bstart[b] = st;
    bcnt[b]  = s;
    bcur[b]  = st;
  }
}

// edata.x = (dst_local<<23) | (src*64) ; edata.y = weight bits.
// Bucket cursors hand out sequential positions -> dense write frontier.
__global__ void fill_edges(const int* __restrict__ ei, const float* __restrict__ dis,
                           int* __restrict__ bcur, int2* __restrict__ edata)
{
  int e = blockIdx.x * 256 + threadIdx.x;
  if (e >= N_EDGE) return;
  int r = ei[e];
  int c = ei[N_EDGE + e];
  float w = dis[r] * dis[c];
  int pos = atomicAdd(&bcur[c >> 6], 1);
  edata[pos] = make_int2(((c & 63) << 23) | (r << 6), __float_as_int(w));
}

// ---------------------------------------------------------------------------
// One propagation step: workgroup per 64-node dst bucket, LDS fp32 accumulator.
// lane = feature; 16 gathers in flight per wave; ds_add_f32 accumulation.
// ---------------------------------------------------------------------------
__global__ __launch_bounds__(256) void prop_step(
    const _Float16* __restrict__ cur, _Float16* __restrict__ nxt,
    const float* __restrict__ dis, const int* __restrict__ bstart,
    const int* __restrict__ bcnt, const int2* __restrict__ edata,
    float* __restrict__ hid, const float* __restrict__ temp, int kk)
{
  __shared__ float accs[64 * 48];   // 12KB: [local][feature]
  const int b   = blockIdx.x;
  const int tid = threadIdx.x;
  const int f   = tid & 63;
  const int wv  = tid >> 6;
  const int fc  = f < NCLS ? f : NCLS;   // keep load inside the 128B row
  const bool act = f < NCLS;

  for (int i = tid; i < 64 * 48; i += 256) accs[i] = 0.f;
  __syncthreads();

  const int s0 = bstart[b];
  const int n  = bcnt[b];
  const int2* ep = edata + s0;

  const int nfull = n & ~15;
  for (int j = wv * 16; j < nfull; j += 64) {
    int4 m[8];
    #pragma unroll
    for (int q = 0; q < 8; ++q) m[q] = *(const int4*)(ep + j + q * 2);
    float v[16];
    #pragma unroll
    for (int q = 0; q < 8; ++q) {
      v[2 * q]     = (float)cur[(m[q].x & 0x7fffff) + fc];
      v[2 * q + 1] = (float)cur[(m[q].z & 0x7fffff) + fc];
    }
    if (act) {
      #pragma unroll
      for (int q = 0; q < 8; ++q) {
        atomicAdd(&accs[(((unsigned)m[q].x) >> 23) * 48 + f],
                  __int_as_float(m[q].y) * v[2 * q]);
        atomicAdd(&accs[(((unsigned)m[q].z) >> 23) * 48 + f],
                  __int_as_float(m[q].w) * v[2 * q + 1]);
      }
    }
  }
  if (wv == 0) {
    for (int j = nfull; j < n; ++j) {
      int2 e = ep[j];
      float v = (float)cur[(e.x & 0x7fffff) + fc];
      if (act) atomicAdd(&accs[(((unsigned)e.x) >> 23) * 48 + f],
                         __int_as_float(e.y) * v);
    }
  }
  __syncthreads();

  const float tk = temp[kk];
  for (int t = 0; t < 16; ++t) {
    int local = wv * 16 + t;
    int wid = b * 64 + local;
    if (wid >= N_NODES) break;
    float dv = dis[wid];
    float self = dv * dv * (float)cur[wid * CP2 + fc];
    if (act) {
      float val = accs[local * 48 + f] + self;
      nxt[wid * CP2 + f] = (_Float16)val;
      hid[(size_t)wid * NCLS + f] += tk * val;
    }
  }
}

// ---------------------------------------------------------------------------
extern "C" void kernel_launch(void* const* d_in, const int* in_sizes, int n_in,
                              void* d_out, int out_size, void* d_ws, size_t ws_size,
                              hipStream_t stream)
{
  const float* x    = (const float*)d_in[0];
  const int*   ei   = (const int*)d_in[1];     // [2,E] int32: rows then cols
  const float* W1   = (const float*)d_in[2];
  const float* b1   = (const float*)d_in[3];
  const float* W2   = (const float*)d_in[4];
  const float* b2   = (const float*)d_in[5];
  const float* temp = (const float*)d_in[6];
  float* out_ls  = (float*)d_out;
  float* out_hid = out_ls + (size_t)N_NODES * NCLS;

  char* ws = (char*)d_ws;
  size_t off = 0;
  auto alloc = [&](size_t bytes) -> void* {
    void* p = ws + off;
    off += (bytes + 255) & ~(size_t)255;
    return p;
  };
  _Float16* h    = (_Float16*)alloc((size_t)N_NODES * HID * sizeof(_Float16));
  _Float16* bufA = (_Float16*)alloc(((size_t)N_NODES * CP2 + 64) * sizeof(_Float16));
  _Float16* bufB = (_Float16*)alloc(((size_t)N_NODES * CP2 + 64) * sizeof(_Float16));
  int*   counts  = (int*)alloc((size_t)N_NODES * sizeof(int));
  int*   bstart  = (int*)alloc((size_t)NBUCK * sizeof(int));
  int*   bcnt    = (int*)alloc((size_t)NBUCK * sizeof(int));
  int*   bcur    = (int*)alloc((size_t)NBUCK * sizeof(int));
  float* dis     = (float*)alloc((size_t)N_NODES * sizeof(float));
  int*   cursor  = (int*)alloc(256);
  int2*  edata   = (int2*)alloc(((size_t)N_EDGE + 4096) * sizeof(int2));
  (void)ws_size; (void)in_sizes; (void)n_in; (void)out_size;

  const int gemm_blocks = (N_NODES + 127) / 128;           // 782
  gemm1_relu<<<gemm_blocks, 256, 0, stream>>>(x, W1, b1, h);
  gemm2_fused<<<gemm_blocks, 256, 0, stream>>>(h, W2, b2, temp, out_ls, out_hid, bufA);
  init_counts<<<(N_NODES + 255) / 256, 256, 0, stream>>>(counts, cursor);
  count_edges<<<(N_EDGE + 255) / 256, 256, 0, stream>>>(ei + N_EDGE, counts);
  bucket_scan<<<(NBUCK + 255) / 256, 256, 0, stream>>>(counts, dis, bstart, bcnt, bcur, cursor);
  fill_edges<<<(N_EDGE + 255) / 256, 256, 0, stream>>>(ei, dis, bcur, edata);

  _Float16* cur = bufA; _Float16* nxt = bufB;
  for (int k = 0; k < K_PROP; ++k) {
    prop_step<<<NBUCK, 256, 0, stream>>>(cur, nxt, dis, bstart, bcnt,
                                         edata, out_hid, temp, k + 1);
    _Float16* t = cur; cur = nxt; nxt = t;
  }
}

// Round 4
// 2166.317 us; speedup vs baseline: 4.4758x; 4.4758x over previous
//
#include <hip/hip_runtime.h>
#include <hip/hip_bf16.h>
#include <hip/hip_fp8.h>
#include <math.h>

#define N_NODES 100000
#define F_IN    500
#define HID     64
#define NCLS    47
#define CP8     64      // fp8 row stride for propagation buffers: 64B = 1 cache line
#define N_EDGE  3200000
#define K_PROP  10
#define NBUCK   1563    // ceil(N_NODES/64)

typedef _Float16 v8h  __attribute__((ext_vector_type(8)));
typedef _Float16 v4hh __attribute__((ext_vector_type(4)));
typedef float    v4f  __attribute__((ext_vector_type(4)));

__device__ inline float f8tof(unsigned char b) {
  __hip_fp8_e4m3 t; t.__x = (__hip_fp8_storage_t)b; return (float)t;
}
__device__ inline unsigned char ftof8(float v) {
  __hip_fp8_e4m3 t(v); return (unsigned char)t.__x;
}

// ---------------------------------------------------------------------------
// GEMM1: h[N,64] = relu(x[N,500] @ W1[500,64] + b1), f16 output for GEMM2.
// ---------------------------------------------------------------------------
__global__ __launch_bounds__(256) void gemm1_relu(
    const float* __restrict__ x, const float* __restrict__ W1,
    const float* __restrict__ b1, _Float16* __restrict__ h)
{
  __shared__ _Float16 xa[128][40];
  __shared__ _Float16 wb[64][40];
  const int tid  = threadIdx.x;
  const int lane = tid & 63;
  const int wv   = tid >> 6;
  const int l15  = lane & 15;
  const int quad = lane >> 4;
  const int row0 = blockIdx.x * 128;

  v4f acc[2][4] = {};

  for (int k0 = 0; k0 < F_IN; k0 += 32) {
    #pragma unroll
    for (int i = 0; i < 4; ++i) {
      int f = tid + i * 256;
      int r = f >> 3, q = f & 7;
      int gr = row0 + r;
      int kk = k0 + q * 4;
      float v0 = 0.f, v1 = 0.f, v2 = 0.f, v3 = 0.f;
      if (gr < N_NODES) {
        if (kk + 3 < F_IN) {
          const float4 v = *(const float4*)(x + (size_t)gr * F_IN + kk);
          v0 = v.x; v1 = v.y; v2 = v.z; v3 = v.w;
        } else {
          const float* xp = x + (size_t)gr * F_IN;
          if (kk + 0 < F_IN) v0 = xp[kk + 0];
          if (kk + 1 < F_IN) v1 = xp[kk + 1];
          if (kk + 2 < F_IN) v2 = xp[kk + 2];
          if (kk + 3 < F_IN) v3 = xp[kk + 3];
        }
      }
      v4hh pk = {(_Float16)v0, (_Float16)v1, (_Float16)v2, (_Float16)v3};
      *(v4hh*)&xa[r][q * 4] = pk;
    }
    #pragma unroll
    for (int i = 0; i < 2; ++i) {
      int f = tid + i * 256;
      int k = f >> 4, c4 = (f & 15) * 4;
      int gk = k0 + k;
      float4 v = make_float4(0.f, 0.f, 0.f, 0.f);
      if (gk < F_IN) v = *(const float4*)(W1 + (size_t)gk * HID + c4);
      wb[c4 + 0][k] = (_Float16)v.x; wb[c4 + 1][k] = (_Float16)v.y;
      wb[c4 + 2][k] = (_Float16)v.z; wb[c4 + 3][k] = (_Float16)v.w;
    }
    __syncthreads();
    const int m0 = wv * 32;
    v8h a0 = *(const v8h*)&xa[m0 + l15][quad * 8];
    v8h a1 = *(const v8h*)&xa[m0 + 16 + l15][quad * 8];
    #pragma unroll
    for (int nt = 0; nt < 4; ++nt) {
      v8h b = *(const v8h*)&wb[nt * 16 + l15][quad * 8];
      acc[0][nt] = __builtin_amdgcn_mfma_f32_16x16x32_f16(a0, b, acc[0][nt], 0, 0, 0);
      acc[1][nt] = __builtin_amdgcn_mfma_f32_16x16x32_f16(a1, b, acc[1][nt], 0, 0, 0);
    }
    __syncthreads();
  }
  const int m0 = wv * 32;
  float b1v[4];
  #pragma unroll
  for (int nt = 0; nt < 4; ++nt) b1v[nt] = b1[nt * 16 + l15];
  #pragma unroll
  for (int mi = 0; mi < 2; ++mi)
    #pragma unroll
    for (int r = 0; r < 4; ++r) {
      int grow = row0 + m0 + mi * 16 + quad * 4 + r;
      if (grow < N_NODES) {
        #pragma unroll
        for (int nt = 0; nt < 4; ++nt) {
          float v = fmaxf(acc[mi][nt][r] + b1v[nt], 0.f);
          h[(size_t)grow * HID + nt * 16 + l15] = (_Float16)v;
        }
      }
    }
}

// ---------------------------------------------------------------------------
// GEMM2 fused: z = h @ W2 + b2 ; out_ls = log_softmax(z) ; out_hid = temp0*z ;
// cur = z (fp8 e4m3, stride CP8 bytes).
// ---------------------------------------------------------------------------
__global__ __launch_bounds__(256) void gemm2_fused(
    const _Float16* __restrict__ h, const float* __restrict__ W2,
    const float* __restrict__ b2, const float* __restrict__ temp,
    float* __restrict__ out_ls, float* __restrict__ out_hid,
    unsigned char* __restrict__ cur)
{
  __shared__ _Float16 ha[128][72];
  __shared__ _Float16 wb[64][72];
  __shared__ float b2s[64];
  const int tid  = threadIdx.x;
  const int lane = tid & 63;
  const int wv   = tid >> 6;
  const int l15  = lane & 15;
  const int quad = lane >> 4;
  const int row0 = blockIdx.x * 128;

  for (int i = tid; i < 64 * 72; i += 256) ((_Float16*)wb)[i] = (_Float16)0.f;
  if (tid < 64) b2s[tid] = (tid < NCLS) ? b2[tid] : 0.f;
  __syncthreads();
  for (int i = tid; i < HID * NCLS; i += 256) {
    int k = i / NCLS, n = i % NCLS;
    wb[n][k] = (_Float16)W2[i];
  }
  const unsigned short* hu = (const unsigned short*)h;
  #pragma unroll
  for (int i = 0; i < 8; ++i) {
    int f = tid + i * 256;
    int r = f >> 4, q = (f & 15) * 4;
    int gr = row0 + r;
    ushort4 v = make_ushort4(0, 0, 0, 0);
    if (gr < N_NODES) v = *(const ushort4*)(hu + (size_t)gr * HID + q);
    *(ushort4*)((unsigned short*)&ha[r][0] + q) = v;
  }
  __syncthreads();

  const int m0 = wv * 32;
  v4f acc[2][4] = {};
  #pragma unroll
  for (int ks = 0; ks < 2; ++ks) {
    v8h a0 = *(const v8h*)&ha[m0 + l15][ks * 32 + quad * 8];
    v8h a1 = *(const v8h*)&ha[m0 + 16 + l15][ks * 32 + quad * 8];
    #pragma unroll
    for (int nt = 0; nt < 4; ++nt) {
      v8h b = *(const v8h*)&wb[nt * 16 + l15][ks * 32 + quad * 8];
      acc[0][nt] = __builtin_amdgcn_mfma_f32_16x16x32_f16(a0, b, acc[0][nt], 0, 0, 0);
      acc[1][nt] = __builtin_amdgcn_mfma_f32_16x16x32_f16(a1, b, acc[1][nt], 0, 0, 0);
    }
  }

  const float t0 = temp[0];
  float b2v[4];
  #pragma unroll
  for (int nt = 0; nt < 4; ++nt) b2v[nt] = b2s[nt * 16 + l15];

  #pragma unroll
  for (int mi = 0; mi < 2; ++mi)
    #pragma unroll
    for (int r = 0; r < 4; ++r) {
      int grow = row0 + m0 + mi * 16 + quad * 4 + r;
      float v[4]; float mx = -1e30f;
      #pragma unroll
      for (int nt = 0; nt < 4; ++nt) {
        v[nt] = acc[mi][nt][r] + b2v[nt];
        if (nt * 16 + l15 < NCLS) mx = fmaxf(mx, v[nt]);
      }
      #pragma unroll
      for (int off = 1; off < 16; off <<= 1) mx = fmaxf(mx, __shfl_xor(mx, off));
      float s = 0.f;
      #pragma unroll
      for (int nt = 0; nt < 4; ++nt)
        if (nt * 16 + l15 < NCLS) s += __expf(v[nt] - mx);
      #pragma unroll
      for (int off = 1; off < 16; off <<= 1) s += __shfl_xor(s, off);
      float den = mx + __logf(s);
      if (grow < N_NODES) {
        #pragma unroll
        for (int nt = 0; nt < 4; ++nt) {
          int c = nt * 16 + l15;
          if (c < NCLS) {
            float z = v[nt];
            out_ls [(size_t)grow * NCLS + c] = z - den;
            out_hid[(size_t)grow * NCLS + c] = t0 * z;
            cur    [(size_t)grow * CP8  + c] = ftof8(z);
          }
        }
      }
    }
}

// ---------------------------------------------------------------------------
// Graph prep: counts -> dis + per-bucket segments -> dense bucket fill ->
// in-bucket reorder to per-node segments (dense write window).
// ---------------------------------------------------------------------------
__global__ void init_counts(int* counts, int* cursor)
{
  int i = blockIdx.x * 256 + threadIdx.x;
  if (i < N_NODES) counts[i] = 0;
  if (i == 0) *cursor = 0;
}

__global__ void count_edges(const int* __restrict__ col, int* __restrict__ counts)
{
  int e = blockIdx.x * 256 + threadIdx.x;
  if (e < N_EDGE) atomicAdd(&counts[col[e]], 1);
}

__global__ void bucket_scan(const int* __restrict__ counts, float* __restrict__ dis,
                            int* __restrict__ bstart, int* __restrict__ bcnt,
                            int* __restrict__ bcur, int* __restrict__ cursor)
{
  int b = blockIdx.x * 256 + threadIdx.x;
  int lane = threadIdx.x & 63;
  int s = 0;
  if (b < NBUCK) {
    int base = b * 64;
    int lim = (N_NODES - base < 64) ? (N_NODES - base) : 64;
    for (int j = 0; j < lim; ++j) {
      int c = counts[base + j];
      s += c;
      dis[base + j] = rsqrtf((float)(c + 1));   // deg = in-edges + self loop
    }
  }
  int sz = (s + 1) & ~1;
  int incl = sz;
  #pragma unroll
  for (int off = 1; off < 64; off <<= 1) {
    int t = __shfl_up(incl, off);
    if (lane >= off) incl += t;
  }
  int base0 = 0;
  if (lane == 63) base0 = atomicAdd(cursor, incl);
  base0 = __shfl(base0, 63);
  if (b < NBUCK) {
    int st = base0 + incl - sz;
    bstart[b] = st;
    bcnt[b]  = s;
    bcur[b]  = st;
  }
}

// edata.x = (dst_local<<23) | (src*64) ; edata.y = weight bits.
__global__ void fill_edges(const int* __restrict__ ei, const float* __restrict__ dis,
                           int* __restrict__ bcur, int2* __restrict__ edata)
{
  int e = blockIdx.x * 256 + threadIdx.x;
  if (e >= N_EDGE) return;
  int r = ei[e];
  int c = ei[N_EDGE + e];
  float w = dis[r] * dis[c];
  int pos = atomicAdd(&bcur[c >> 6], 1);
  edata[pos] = make_int2(((c & 63) << 23) | (r << 6), __float_as_int(w));
}

// One WG per bucket: per-node starts via wave scan; scatter bucket edges into
// per-node segments (writes confined to the bucket's ~16KB window).
// LDS cursors are int -> native ds_add_rtn_u32.
__global__ __launch_bounds__(256) void reorder(
    const int* __restrict__ counts, const int* __restrict__ bstart,
    const int* __restrict__ bcnt, const int2* __restrict__ edin,
    int2* __restrict__ edout, int* __restrict__ nstart)
{
  __shared__ int lcur[64];
  const int b = blockIdx.x;
  const int tid = threadIdx.x;
  if (tid < 64) {
    int node = b * 64 + tid;
    int c = (node < N_NODES) ? counts[node] : 0;
    int incl = c;
    #pragma unroll
    for (int off = 1; off < 64; off <<= 1) {
      int t = __shfl_up(incl, off);
      if (tid >= off) incl += t;
    }
    int st = bstart[b] + incl - c;
    lcur[tid] = st;
    if (node < N_NODES) nstart[node] = st;
  }
  __syncthreads();
  const int n = bcnt[b], bs = bstart[b];
  for (int j = tid; j < n; j += 256) {
    int2 e = edin[bs + j];
    int local = ((unsigned)e.x) >> 23;
    int pos = atomicAdd(&lcur[local], 1);
    edout[pos] = make_int2(e.x & 0x7fffff, e.y);
  }
}

// ---------------------------------------------------------------------------
// One propagation step (pull): wave per dst node, lane = feature.
// fp8 rows: each gather = exactly one 64B line. 16 gathers in flight.
// ---------------------------------------------------------------------------
__global__ __launch_bounds__(256) void prop_step(
    const unsigned char* __restrict__ cur, unsigned char* __restrict__ nxt,
    const float* __restrict__ dis, const int* __restrict__ nstart,
    const int* __restrict__ cnt, const int2* __restrict__ edata,
    float* __restrict__ hid, const float* __restrict__ temp, int kk)
{
  int wid = blockIdx.x * 4 + (threadIdx.x >> 6);
  int f   = threadIdx.x & 63;
  if (wid >= N_NODES) return;
  int fc = f < NCLS ? f : NCLS;           // clamp inside the 64B row
  float dv = dis[wid];
  float acc = dv * dv * f8tof(cur[wid * CP8 + fc]);
  int s0 = nstart[wid], n = cnt[wid];
  const int2* ep = edata + s0;
  int j = 0;
  for (; j + 16 <= n; j += 16) {
    int4 m[8];
    #pragma unroll
    for (int q = 0; q < 8; ++q) m[q] = *(const int4*)(ep + j + q * 2);
    unsigned char cb[16];
    #pragma unroll
    for (int q = 0; q < 8; ++q) {
      cb[2 * q]     = cur[m[q].x + fc];
      cb[2 * q + 1] = cur[m[q].z + fc];
    }
    #pragma unroll
    for (int q = 0; q < 8; ++q) {
      acc += __int_as_float(m[q].y) * f8tof(cb[2 * q]);
      acc += __int_as_float(m[q].w) * f8tof(cb[2 * q + 1]);
    }
  }
  for (; j < n; ++j) {
    int2 ed = ep[j];
    acc += __int_as_float(ed.y) * f8tof(cur[ed.x + fc]);
  }
  if (f < NCLS) {
    nxt[wid * CP8 + f] = ftof8(acc);
    hid[(size_t)wid * NCLS + f] += temp[kk] * acc;
  }
}

// ---------------------------------------------------------------------------
extern "C" void kernel_launch(void* const* d_in, const int* in_sizes, int n_in,
                              void* d_out, int out_size, void* d_ws, size_t ws_size,
                              hipStream_t stream)
{
  const float* x    = (const float*)d_in[0];
  const int*   ei   = (const int*)d_in[1];     // [2,E] int32: rows then cols
  const float* W1   = (const float*)d_in[2];
  const float* b1   = (const float*)d_in[3];
  const float* W2   = (const float*)d_in[4];
  const float* b2   = (const float*)d_in[5];
  const float* temp = (const float*)d_in[6];
  float* out_ls  = (float*)d_out;
  float* out_hid = out_ls + (size_t)N_NODES * NCLS;

  char* ws = (char*)d_ws;
  size_t off = 0;
  auto alloc = [&](size_t bytes) -> void* {
    void* p = ws + off;
    off += (bytes + 255) & ~(size_t)255;
    return p;
  };
  _Float16* h    = (_Float16*)alloc((size_t)N_NODES * HID * sizeof(_Float16));
  unsigned char* bufA = (unsigned char*)alloc((size_t)N_NODES * CP8 + 256);
  unsigned char* bufB = (unsigned char*)alloc((size_t)N_NODES * CP8 + 256);
  int*   counts  = (int*)alloc((size_t)N_NODES * sizeof(int));
  int*   bstart  = (int*)alloc((size_t)NBUCK * sizeof(int));
  int*   bcnt    = (int*)alloc((size_t)NBUCK * sizeof(int));
  int*   bcur    = (int*)alloc((size_t)NBUCK * sizeof(int));
  int*   nstart  = (int*)alloc((size_t)N_NODES * sizeof(int));
  float* dis     = (float*)alloc((size_t)N_NODES * sizeof(float));
  int*   cursor  = (int*)alloc(256);
  int2*  edata   = (int2*)alloc(((size_t)N_EDGE + 4096) * sizeof(int2));
  int2*  edata2  = (int2*)alloc(((size_t)N_EDGE + 4096) * sizeof(int2));
  (void)ws_size; (void)in_sizes; (void)n_in; (void)out_size;

  const int gemm_blocks = (N_NODES + 127) / 128;           // 782
  gemm1_relu<<<gemm_blocks, 256, 0, stream>>>(x, W1, b1, h);
  gemm2_fused<<<gemm_blocks, 256, 0, stream>>>(h, W2, b2, temp, out_ls, out_hid, bufA);
  init_counts<<<(N_NODES + 255) / 256, 256, 0, stream>>>(counts, cursor);
  count_edges<<<(N_EDGE + 255) / 256, 256, 0, stream>>>(ei + N_EDGE, counts);
  bucket_scan<<<(NBUCK + 255) / 256, 256, 0, stream>>>(counts, dis, bstart, bcnt, bcur, cursor);
  fill_edges<<<(N_EDGE + 255) / 256, 256, 0, stream>>>(ei, dis, bcur, edata);
  reorder<<<NBUCK, 256, 0, stream>>>(counts, bstart, bcnt, edata, edata2, nstart);

  unsigned char* cur = bufA; unsigned char* nxt = bufB;
  for (int k = 0; k < K_PROP; ++k) {
    prop_step<<<(N_NODES + 3) / 4, 256, 0, stream>>>(cur, nxt, dis, nstart, counts,
                                                     edata2, out_hid, temp, k + 1);
    unsigned char* t = cur; cur = nxt; nxt = t;
  }
}

// Round 5
// 1655.649 us; speedup vs baseline: 5.8563x; 1.3084x over previous
//
#include <hip/hip_runtime.h>
#include <hip/hip_bf16.h>
#include <hip/hip_fp8.h>
#include <math.h>

#define N_NODES 100000
#define F_IN    500
#define HID     64
#define NCLS    47
#define CP8     64      // fp8 row stride for propagation buffers: 64B = 1 cache line
#define N_EDGE  3200000
#define K_PROP  10
#define NBUCK   1563    // ceil(N_NODES/64)
#define NCHUNK  256
#define CHUNK   12500   // NCHUNK*CHUNK = 3.2M = N_EDGE

typedef _Float16 v8h  __attribute__((ext_vector_type(8)));
typedef _Float16 v4hh __attribute__((ext_vector_type(4)));
typedef float    v4f  __attribute__((ext_vector_type(4)));

__device__ inline float f8tof(unsigned char b) {
  __hip_fp8_e4m3 t; t.__x = (__hip_fp8_storage_t)b; return (float)t;
}
__device__ inline unsigned char ftof8(float v) {
  __hip_fp8_e4m3 t(v); return (unsigned char)t.__x;
}

// ---------------------------------------------------------------------------
// GEMM1: h[N,64] = relu(x[N,500] @ W1[500,64] + b1), f16 output for GEMM2.
// ---------------------------------------------------------------------------
__global__ __launch_bounds__(256) void gemm1_relu(
    const float* __restrict__ x, const float* __restrict__ W1,
    const float* __restrict__ b1, _Float16* __restrict__ h)
{
  __shared__ _Float16 xa[128][40];
  __shared__ _Float16 wb[64][40];
  const int tid  = threadIdx.x;
  const int lane = tid & 63;
  const int wv   = tid >> 6;
  const int l15  = lane & 15;
  const int quad = lane >> 4;
  const int row0 = blockIdx.x * 128;

  v4f acc[2][4] = {};

  for (int k0 = 0; k0 < F_IN; k0 += 32) {
    #pragma unroll
    for (int i = 0; i < 4; ++i) {
      int f = tid + i * 256;
      int r = f >> 3, q = f & 7;
      int gr = row0 + r;
      int kk = k0 + q * 4;
      float v0 = 0.f, v1 = 0.f, v2 = 0.f, v3 = 0.f;
      if (gr < N_NODES) {
        if (kk + 3 < F_IN) {
          const float4 v = *(const float4*)(x + (size_t)gr * F_IN + kk);
          v0 = v.x; v1 = v.y; v2 = v.z; v3 = v.w;
        } else {
          const float* xp = x + (size_t)gr * F_IN;
          if (kk + 0 < F_IN) v0 = xp[kk + 0];
          if (kk + 1 < F_IN) v1 = xp[kk + 1];
          if (kk + 2 < F_IN) v2 = xp[kk + 2];
          if (kk + 3 < F_IN) v3 = xp[kk + 3];
        }
      }
      v4hh pk = {(_Float16)v0, (_Float16)v1, (_Float16)v2, (_Float16)v3};
      *(v4hh*)&xa[r][q * 4] = pk;
    }
    #pragma unroll
    for (int i = 0; i < 2; ++i) {
      int f = tid + i * 256;
      int k = f >> 4, c4 = (f & 15) * 4;
      int gk = k0 + k;
      float4 v = make_float4(0.f, 0.f, 0.f, 0.f);
      if (gk < F_IN) v = *(const float4*)(W1 + (size_t)gk * HID + c4);
      wb[c4 + 0][k] = (_Float16)v.x; wb[c4 + 1][k] = (_Float16)v.y;
      wb[c4 + 2][k] = (_Float16)v.z; wb[c4 + 3][k] = (_Float16)v.w;
    }
    __syncthreads();
    const int m0 = wv * 32;
    v8h a0 = *(const v8h*)&xa[m0 + l15][quad * 8];
    v8h a1 = *(const v8h*)&xa[m0 + 16 + l15][quad * 8];
    #pragma unroll
    for (int nt = 0; nt < 4; ++nt) {
      v8h b = *(const v8h*)&wb[nt * 16 + l15][quad * 8];
      acc[0][nt] = __builtin_amdgcn_mfma_f32_16x16x32_f16(a0, b, acc[0][nt], 0, 0, 0);
      acc[1][nt] = __builtin_amdgcn_mfma_f32_16x16x32_f16(a1, b, acc[1][nt], 0, 0, 0);
    }
    __syncthreads();
  }
  const int m0 = wv * 32;
  float b1v[4];
  #pragma unroll
  for (int nt = 0; nt < 4; ++nt) b1v[nt] = b1[nt * 16 + l15];
  #pragma unroll
  for (int mi = 0; mi < 2; ++mi)
    #pragma unroll
    for (int r = 0; r < 4; ++r) {
      int grow = row0 + m0 + mi * 16 + quad * 4 + r;
      if (grow < N_NODES) {
        #pragma unroll
        for (int nt = 0; nt < 4; ++nt) {
          float v = fmaxf(acc[mi][nt][r] + b1v[nt], 0.f);
          h[(size_t)grow * HID + nt * 16 + l15] = (_Float16)v;
        }
      }
    }
}

// ---------------------------------------------------------------------------
// GEMM2 fused: z = h @ W2 + b2 ; out_ls = log_softmax(z) ; out_hid = temp0*z ;
// cur = z (fp8 e4m3, stride CP8 bytes).
// ---------------------------------------------------------------------------
__global__ __launch_bounds__(256) void gemm2_fused(
    const _Float16* __restrict__ h, const float* __restrict__ W2,
    const float* __restrict__ b2, const float* __restrict__ temp,
    float* __restrict__ out_ls, float* __restrict__ out_hid,
    unsigned char* __restrict__ cur)
{
  __shared__ _Float16 ha[128][72];
  __shared__ _Float16 wb[64][72];
  __shared__ float b2s[64];
  const int tid  = threadIdx.x;
  const int lane = tid & 63;
  const int wv   = tid >> 6;
  const int l15  = lane & 15;
  const int quad = lane >> 4;
  const int row0 = blockIdx.x * 128;

  for (int i = tid; i < 64 * 72; i += 256) ((_Float16*)wb)[i] = (_Float16)0.f;
  if (tid < 64) b2s[tid] = (tid < NCLS) ? b2[tid] : 0.f;
  __syncthreads();
  for (int i = tid; i < HID * NCLS; i += 256) {
    int k = i / NCLS, n = i % NCLS;
    wb[n][k] = (_Float16)W2[i];
  }
  const unsigned short* hu = (const unsigned short*)h;
  #pragma unroll
  for (int i = 0; i < 8; ++i) {
    int f = tid + i * 256;
    int r = f >> 4, q = (f & 15) * 4;
    int gr = row0 + r;
    ushort4 v = make_ushort4(0, 0, 0, 0);
    if (gr < N_NODES) v = *(const ushort4*)(hu + (size_t)gr * HID + q);
    *(ushort4*)((unsigned short*)&ha[r][0] + q) = v;
  }
  __syncthreads();

  const int m0 = wv * 32;
  v4f acc[2][4] = {};
  #pragma unroll
  for (int ks = 0; ks < 2; ++ks) {
    v8h a0 = *(const v8h*)&ha[m0 + l15][ks * 32 + quad * 8];
    v8h a1 = *(const v8h*)&ha[m0 + 16 + l15][ks * 32 + quad * 8];
    #pragma unroll
    for (int nt = 0; nt < 4; ++nt) {
      v8h b = *(const v8h*)&wb[nt * 16 + l15][ks * 32 + quad * 8];
      acc[0][nt] = __builtin_amdgcn_mfma_f32_16x16x32_f16(a0, b, acc[0][nt], 0, 0, 0);
      acc[1][nt] = __builtin_amdgcn_mfma_f32_16x16x32_f16(a1, b, acc[1][nt], 0, 0, 0);
    }
  }

  const float t0 = temp[0];
  float b2v[4];
  #pragma unroll
  for (int nt = 0; nt < 4; ++nt) b2v[nt] = b2s[nt * 16 + l15];

  #pragma unroll
  for (int mi = 0; mi < 2; ++mi)
    #pragma unroll
    for (int r = 0; r < 4; ++r) {
      int grow = row0 + m0 + mi * 16 + quad * 4 + r;
      float v[4]; float mx = -1e30f;
      #pragma unroll
      for (int nt = 0; nt < 4; ++nt) {
        v[nt] = acc[mi][nt][r] + b2v[nt];
        if (nt * 16 + l15 < NCLS) mx = fmaxf(mx, v[nt]);
      }
      #pragma unroll
      for (int off = 1; off < 16; off <<= 1) mx = fmaxf(mx, __shfl_xor(mx, off));
      float s = 0.f;
      #pragma unroll
      for (int nt = 0; nt < 4; ++nt)
        if (nt * 16 + l15 < NCLS) s += __expf(v[nt] - mx);
      #pragma unroll
      for (int off = 1; off < 16; off <<= 1) s += __shfl_xor(s, off);
      float den = mx + __logf(s);
      if (grow < N_NODES) {
        #pragma unroll
        for (int nt = 0; nt < 4; ++nt) {
          int c = nt * 16 + l15;
          if (c < NCLS) {
            float z = v[nt];
            out_ls [(size_t)grow * NCLS + c] = z - den;
            out_hid[(size_t)grow * NCLS + c] = t0 * z;
            cur    [(size_t)grow * CP8  + c] = ftof8(z);
          }
        }
      }
    }
}

// ---------------------------------------------------------------------------
// Graph build: chunked counting sort by 64-node bucket, no global atomics.
// ---------------------------------------------------------------------------

// pass 1: per-(chunk,bucket) histogram via LDS ds_add
__global__ __launch_bounds__(256) void pass1_hist(
    const int* __restrict__ col, int* __restrict__ chunkhist)
{
  __shared__ int hist[NBUCK];
  for (int i = threadIdx.x; i < NBUCK; i += 256) hist[i] = 0;
  __syncthreads();
  const int c = blockIdx.x;
  const int e0 = c * CHUNK;
  const int e1 = (e0 + CHUNK < N_EDGE) ? e0 + CHUNK : N_EDGE;
  for (int e = e0 + threadIdx.x; e < e1; e += 256)
    atomicAdd(&hist[col[e] >> 6], 1);
  __syncthreads();
  for (int i = threadIdx.x; i < NBUCK; i += 256)
    chunkhist[(size_t)c * NBUCK + i] = hist[i];
}

// bucket totals over chunks (coalesced across b)
__global__ void btotals(const int* __restrict__ chunkhist, int* __restrict__ btot)
{
  int b = blockIdx.x * 256 + threadIdx.x;
  if (b >= NBUCK) return;
  int s = 0;
  for (int c = 0; c < NCHUNK; ++c) s += chunkhist[(size_t)c * NBUCK + b];
  btot[b] = s;
}

// exclusive scan over 1563 bucket totals (single WG)
__global__ __launch_bounds__(256) void bscan(
    const int* __restrict__ btot, int* __restrict__ bstart, int* __restrict__ bcnt)
{
  __shared__ int psum[256];
  __shared__ int poff[256];
  const int t = threadIdx.x;
  const int lo = t * 7;
  const int hi = (lo + 7 < NBUCK) ? lo + 7 : NBUCK;
  int s = 0;
  for (int i = lo; i < hi; ++i) s += btot[i];
  psum[t] = s;
  __syncthreads();
  if (t == 0) {
    int run = 0;
    for (int i = 0; i < 256; ++i) { poff[i] = run; run += psum[i]; }
  }
  __syncthreads();
  int run = poff[t];
  for (int i = lo; i < hi; ++i) {
    bstart[i] = run;
    bcnt[i] = btot[i];
    run += btot[i];
  }
}

// per-(chunk,bucket) output base = bstart[b] + prefix over chunks
__global__ void chunkbase_k(const int* __restrict__ chunkhist,
                            const int* __restrict__ bstart, int* __restrict__ cbase)
{
  int b = blockIdx.x * 256 + threadIdx.x;
  if (b >= NBUCK) return;
  int run = bstart[b];
  for (int c = 0; c < NCHUNK; ++c) {
    cbase[(size_t)c * NBUCK + b] = run;
    run += chunkhist[(size_t)c * NBUCK + b];
  }
}

// pass 2: scatter edges into disjoint (chunk,bucket) segments; LDS cursors only.
// packed entry: (dst_local<<17) | src   (src < 2^17, dst_local < 64)
__global__ __launch_bounds__(256) void pass2_scatter(
    const int* __restrict__ ei, const int* __restrict__ cbase,
    int* __restrict__ ed1)
{
  __shared__ int lcur[NBUCK];
  const int c = blockIdx.x;
  for (int i = threadIdx.x; i < NBUCK; i += 256)
    lcur[i] = cbase[(size_t)c * NBUCK + i];
  __syncthreads();
  const int e0 = c * CHUNK;
  const int e1 = (e0 + CHUNK < N_EDGE) ? e0 + CHUNK : N_EDGE;
  for (int e = e0 + threadIdx.x; e < e1; e += 256) {
    int r  = ei[e];
    int cl = ei[N_EDGE + e];
    int pos = atomicAdd(&lcur[cl >> 6], 1);
    ed1[pos] = ((cl & 63) << 17) | r;
  }
}

// per-node degree via per-bucket LDS histogram over the bucket-sorted array
__global__ __launch_bounds__(256) void node_hist(
    const int* __restrict__ ed1, const int* __restrict__ bstart,
    const int* __restrict__ bcnt, int* __restrict__ counts, float* __restrict__ dis)
{
  __shared__ int hh[64];
  const int b = blockIdx.x;
  if (threadIdx.x < 64) hh[threadIdx.x] = 0;
  __syncthreads();
  const int s0 = bstart[b], n = bcnt[b];
  for (int j = threadIdx.x; j < n; j += 256)
    atomicAdd(&hh[(ed1[s0 + j] >> 17) & 63], 1);
  __syncthreads();
  if (threadIdx.x < 64) {
    int node = b * 64 + threadIdx.x;
    if (node < N_NODES) {
      counts[node] = hh[threadIdx.x];
      dis[node] = rsqrtf((float)(hh[threadIdx.x] + 1));  // deg + self loop
    }
  }
}

// reorder within bucket window to per-node segments, attach weights.
// ed2.x = src*64 (byte offset into fp8 rows), ed2.y = weight bits.
__global__ __launch_bounds__(256) void reorder2(
    const int* __restrict__ ed1, const int* __restrict__ bstart,
    const int* __restrict__ bcnt, const int* __restrict__ counts,
    const float* __restrict__ dis, int2* __restrict__ ed2, int* __restrict__ nstart)
{
  __shared__ int lcur[64];
  __shared__ float ldis[64];
  const int b = blockIdx.x, tid = threadIdx.x;
  if (tid < 64) {  // first wave
    int node = b * 64 + tid;
    int cc = (node < N_NODES) ? counts[node] : 0;
    int incl = cc;
    #pragma unroll
    for (int off = 1; off < 64; off <<= 1) {
      int t = __shfl_up(incl, off);
      if (tid >= off) incl += t;
    }
    int st = bstart[b] + incl - cc;
    lcur[tid] = st;
    ldis[tid] = (node < N_NODES) ? dis[node] : 0.f;
    if (node < N_NODES) nstart[node] = st;
  }
  __syncthreads();
  const int s0 = bstart[b], n = bcnt[b];
  for (int j = tid; j < n; j += 256) {
    int e = ed1[s0 + j];
    int local = (e >> 17) & 63;
    int src = e & 0x1ffff;
    float w = dis[src] * ldis[local];
    int pos = atomicAdd(&lcur[local], 1);
    ed2[pos] = make_int2(src << 6, __float_as_int(w));
  }
}

// ---------------------------------------------------------------------------
// One propagation step (pull): wave per dst node, lane = feature.
// fp8 rows: each gather = exactly one 64B line. 16 gathers in flight.
// ---------------------------------------------------------------------------
__global__ __launch_bounds__(256) void prop_step(
    const unsigned char* __restrict__ cur, unsigned char* __restrict__ nxt,
    const float* __restrict__ dis, const int* __restrict__ nstart,
    const int* __restrict__ cnt, const int2* __restrict__ edata,
    float* __restrict__ hid, const float* __restrict__ temp, int kk)
{
  int wid = blockIdx.x * 4 + (threadIdx.x >> 6);
  int f   = threadIdx.x & 63;
  if (wid >= N_NODES) return;
  int fc = f < NCLS ? f : NCLS;           // clamp inside the 64B row
  float dv = dis[wid];
  float acc = dv * dv * f8tof(cur[wid * CP8 + fc]);
  int s0 = nstart[wid], n = cnt[wid];
  const int2* ep = edata + s0;
  int j = 0;
  for (; j + 16 <= n; j += 16) {
    int4 m[8];
    #pragma unroll
    for (int q = 0; q < 8; ++q) m[q] = *(const int4*)(ep + j + q * 2);
    unsigned char cb[16];
    #pragma unroll
    for (int q = 0; q < 8; ++q) {
      cb[2 * q]     = cur[m[q].x + fc];
      cb[2 * q + 1] = cur[m[q].z + fc];
    }
    #pragma unroll
    for (int q = 0; q < 8; ++q) {
      acc += __int_as_float(m[q].y) * f8tof(cb[2 * q]);
      acc += __int_as_float(m[q].w) * f8tof(cb[2 * q + 1]);
    }
  }
  for (; j < n; ++j) {
    int2 ed = ep[j];
    acc += __int_as_float(ed.y) * f8tof(cur[ed.x + fc]);
  }
  if (f < NCLS) {
    nxt[wid * CP8 + f] = ftof8(acc);
    hid[(size_t)wid * NCLS + f] += temp[kk] * acc;
  }
}

// ---------------------------------------------------------------------------
extern "C" void kernel_launch(void* const* d_in, const int* in_sizes, int n_in,
                              void* d_out, int out_size, void* d_ws, size_t ws_size,
                              hipStream_t stream)
{
  const float* x    = (const float*)d_in[0];
  const int*   ei   = (const int*)d_in[1];     // [2,E] int32: rows then cols
  const float* W1   = (const float*)d_in[2];
  const float* b1   = (const float*)d_in[3];
  const float* W2   = (const float*)d_in[4];
  const float* b2   = (const float*)d_in[5];
  const float* temp = (const float*)d_in[6];
  float* out_ls  = (float*)d_out;
  float* out_hid = out_ls + (size_t)N_NODES * NCLS;

  char* ws = (char*)d_ws;
  size_t off = 0;
  auto alloc = [&](size_t bytes) -> void* {
    void* p = ws + off;
    off += (bytes + 255) & ~(size_t)255;
    return p;
  };
  _Float16* h    = (_Float16*)alloc((size_t)N_NODES * HID * sizeof(_Float16));
  unsigned char* bufA = (unsigned char*)alloc((size_t)N_NODES * CP8 + 256);
  unsigned char* bufB = (unsigned char*)alloc((size_t)N_NODES * CP8 + 256);
  int*   chunkhist = (int*)alloc((size_t)NCHUNK * NBUCK * sizeof(int));
  int*   cbase     = (int*)alloc((size_t)NCHUNK * NBUCK * sizeof(int));
  int*   btot      = (int*)alloc((size_t)NBUCK * sizeof(int));
  int*   bstart    = (int*)alloc((size_t)NBUCK * sizeof(int));
  int*   bcnt      = (int*)alloc((size_t)NBUCK * sizeof(int));
  int*   counts    = (int*)alloc((size_t)N_NODES * sizeof(int));
  int*   nstart    = (int*)alloc((size_t)N_NODES * sizeof(int));
  float* dis       = (float*)alloc((size_t)N_NODES * sizeof(float));
  int*   ed1       = (int*)alloc(((size_t)N_EDGE + 256) * sizeof(int));
  int2*  ed2       = (int2*)alloc(((size_t)N_EDGE + 256) * sizeof(int2));
  (void)ws_size; (void)in_sizes; (void)n_in; (void)out_size;

  const int gemm_blocks = (N_NODES + 127) / 128;           // 782
  gemm1_relu<<<gemm_blocks, 256, 0, stream>>>(x, W1, b1, h);
  gemm2_fused<<<gemm_blocks, 256, 0, stream>>>(h, W2, b2, temp, out_ls, out_hid, bufA);

  pass1_hist<<<NCHUNK, 256, 0, stream>>>(ei + N_EDGE, chunkhist);
  btotals<<<(NBUCK + 255) / 256, 256, 0, stream>>>(chunkhist, btot);
  bscan<<<1, 256, 0, stream>>>(btot, bstart, bcnt);
  chunkbase_k<<<(NBUCK + 255) / 256, 256, 0, stream>>>(chunkhist, bstart, cbase);
  pass2_scatter<<<NCHUNK, 256, 0, stream>>>(ei, cbase, ed1);
  node_hist<<<NBUCK, 256, 0, stream>>>(ed1, bstart, bcnt, counts, dis);
  reorder2<<<NBUCK, 256, 0, stream>>>(ed1, bstart, bcnt, counts, dis, ed2, nstart);

  unsigned char* cur = bufA; unsigned char* nxt = bufB;
  for (int k = 0; k < K_PROP; ++k) {
    prop_step<<<(N_NODES + 3) / 4, 256, 0, stream>>>(cur, nxt, dis, nstart, counts,
                                                     ed2, out_hid, temp, k + 1);
    unsigned char* t = cur; cur = nxt; nxt = t;
  }
}